// Round 7
// baseline (505.655 us; speedup 1.0000x reference)
//
#include <hip/hip_runtime.h>
#include <float.h>
#include <math.h>

#define B_  8
#define H_  8
#define L_  2048
#define D_  64
#define NS  40          // num selected = min(5*ceil(ln(2048)), 2048) = 40
#define BH  (B_*H_)
#define SCALE 0.125f    // d^-0.5

// XCD swizzle: MI355X dispatches block b to XCD (b % 8).  We remap so that
// bh % 8 == b % 8 for every kernel -> all blocks of one bh run on one XCD,
// keeping that bh's k/v/measure/attn slices resident in its 4MB L2.

// DPP helper: x += lane_shifted_down_by<SHR>(x), within rows of 16 lanes,
// out-of-row reads return 0 (bound_ctrl).  Pure VALU - no LDS pipe.
template<int CTRL>
__device__ __forceinline__ float dpp_add(float x) {
    int s = __builtin_amdgcn_update_dpp(0, __float_as_int(x), CTRL, 0xF, 0xF, true);
    return x + __int_as_float(s);
}

// ---------------------------------------------------------------------------
// K1: sparsity measure.  R9: LDS-tiled gather.  The R3-R6 versions were bound
// by L2 scattered-line throughput (1.34 GB of random 64B lines @ ~17 TB/s =
// ~79us; instr-count cuts changed nothing).  Now: 256 blocks = bh x 4 query
// chunks (1 block/CU, 512 thr), loop over 4 k-tiles of 512 rows: stage tile
// to LDS (128 KB, swizzled f4 j -> (j+row)&15 so octet b128 reads are
// bank-spread), then each wave serves its 64 queries' in-tile samples from
// LDS.  Octet assignment via ballot + m&=m-1 set-bit ladder.  Per-sample dot
// keeps the exact octet/DPP FP order of R3-R6; per-query stats live in lane
// qq's registers across tiles.
// ---------------------------------------------------------------------------
__global__ __launch_bounds__(512) void measure_kernel(
    const float* __restrict__ q, const float* __restrict__ k,
    const int* __restrict__ ridx, float* __restrict__ measure)
{
    __shared__ float4 kt[512 * 16];     // row r, f4 j stored at r*16 + ((j+r)&15)
    int t = threadIdx.x;
    int wv = t >> 6, lane = t & 63;
    int b = blockIdx.x;
    int xcd = b & 7, s = b >> 3;        // s in 0..31
    int bh  = xcd + ((s & 7) << 3);     // 8 bh per XCD
    int chunk = s >> 3;                 // 0..3
    int qbase = chunk * 512 + wv * 64;  // this wave's 64 queries
    int oct = lane >> 3, e = lane & 7;

    const float4* kb  = (const float4*)(k + (size_t)bh * L_ * D_);
    const float4* qb4 = (const float4*)(q + (size_t)bh * L_ * D_);

    float mxq = -FLT_MAX, smq = 0.f;    // lane qq owns query qbase+qq

    for (int T = 0; T < 4; ++T) {
        __syncthreads();                 // reuse guard
        #pragma unroll
        for (int it = 0; it < 16; ++it) {           // stage 512 rows, swizzled
            int f = t + 512*it;
            int row = f >> 4, j = f & 15;
            kt[row*16 + ((j + row) & 15)] = kb[(size_t)(T*512 + row)*16 + j];
        }
        __syncthreads();

        for (int qq = 0; qq < 64; ++qq) {
            int i = qbase + qq;
            int rl = ridx[i * NS + (lane < NS ? lane : NS - 1)];
            unsigned long long M = __ballot((lane < NS) && ((rl >> 9) == T));
            float4 qa = qb4[(size_t)i*16 + e];       // dims 4e..4e+3
            float4 qc = qb4[(size_t)i*16 + e + 8];   // dims 32+4e..
            unsigned long long m = M;
            #pragma unroll
            for (int c = 0; c < 7; ++c) if (c < oct) m &= m - 1;  // skip to oct-th bit

            float mxt = -FLT_MAX, smt = 0.f;
            while (__ballot(m != 0ULL)) {
                bool valid = (m != 0ULL);
                int pos = valid ? ((int)__ffsll((long long)m) - 1) : 0;
                int r  = __shfl(rl, pos, 64);        // sample's k row
                int lr = r & 511;                    // local row in tile
                float4 ka = kt[lr*16 + ((e + lr) & 15)];
                float4 kc = kt[lr*16 + ((e + 8 + lr) & 15)];
                float pp = qa.x*ka.x + qa.y*ka.y + qa.z*ka.z + qa.w*ka.w
                         + qc.x*kc.x + qc.y*kc.y + qc.z*kc.z + qc.w*kc.w;
                pp = dpp_add<0x111>(pp);             // octet tree-sum
                pp = dpp_add<0x112>(pp);
                pp = dpp_add<0x114>(pp);             // holder = lane 8o+7
                if (valid) { mxt = fmaxf(mxt, pp); smt += pp; }
                #pragma unroll
                for (int c = 0; c < 8; ++c) m &= m - 1;   // advance 8 ranks
            }
            // combine the 8 octet-holders (lanes 7,15,...,63)
            mxt = fmaxf(mxt, __shfl_xor(mxt,  8, 64)); smt += __shfl_xor(smt,  8, 64);
            mxt = fmaxf(mxt, __shfl_xor(mxt, 16, 64)); smt += __shfl_xor(smt, 16, 64);
            mxt = fmaxf(mxt, __shfl_xor(mxt, 32, 64)); smt += __shfl_xor(smt, 32, 64);
            float bmx = __shfl(mxt, 7, 64);
            float bsm = __shfl(smt, 7, 64);
            if (lane == qq) { mxq = fmaxf(mxq, bmx); smq += bsm; }
        }
    }
    measure[(size_t)bh * L_ + qbase + lane] = mxq - smq * (1.0f / (float)L_);
}

// ---------------------------------------------------------------------------
// K2: top-NS per (b,h).  Barrier-free segmented tournament (R6): each wave
// extracts its 512-row segment's sorted top-40 in-wave, one barrier, wave 0
// merges the 4 sorted lists.  Comparator: (value desc, index asc).
// ---------------------------------------------------------------------------
__global__ __launch_bounds__(256) void topk_kernel(
    const float* __restrict__ measure, int* __restrict__ idxOut)
{
    __shared__ float segVal[4][NS];
    __shared__ int   segIdx[4][NS];
    int bh = blockIdx.x;
    int t = threadIdx.x, w = t >> 6, lane = t & 63;
    const float4* m4 = (const float4*)(measure + (size_t)bh * L_);

    float vals[8];
    float4 a  = m4[128*w + 2*lane];
    float4 bb = m4[128*w + 2*lane + 1];
    vals[0]=a.x;  vals[1]=a.y;  vals[2]=a.z;  vals[3]=a.w;
    vals[4]=bb.x; vals[5]=bb.y; vals[6]=bb.z; vals[7]=bb.w;
    int gbase = 512*w + 8*lane;

    float lv = -FLT_MAX; int li = 0x7fffffff;
    #pragma unroll
    for (int e = 0; e < 8; ++e)
        if (vals[e] > lv) { lv = vals[e]; li = gbase + e; }

    for (int r = 0; r < NS; ++r) {
        float v = lv; int idx = li;
        #pragma unroll
        for (int off = 32; off; off >>= 1) {
            float ov = __shfl_xor(v, off, 64);
            int   oi = __shfl_xor(idx, off, 64);
            if (ov > v || (ov == v && oi < idx)) { v = ov; idx = oi; }
        }
        if (lane == 0) { segVal[w][r] = v; segIdx[w][r] = idx; }
        if (((idx >> 3) & 63) == lane) {
            int slot = idx & 7;
            #pragma unroll
            for (int e = 0; e < 8; ++e) if (e == slot) vals[e] = -FLT_MAX;
            lv = -FLT_MAX; li = 0x7fffffff;
            #pragma unroll
            for (int e = 0; e < 8; ++e)
                if (vals[e] > lv) { lv = vals[e]; li = gbase + e; }
        }
    }
    __syncthreads();

    if (w == 0) {
        int s = lane & 3;
        int h = 0;
        float hv = segVal[s][0]; int hi_ = segIdx[s][0];
        for (int r = 0; r < NS; ++r) {
            float v = hv; int idx = hi_; int ws = s;
            float ov = __shfl_xor(v, 1, 64); int oi = __shfl_xor(idx, 1, 64); int os = __shfl_xor(ws, 1, 64);
            if (ov > v || (ov == v && oi < idx)) { v = ov; idx = oi; ws = os; }
            ov = __shfl_xor(v, 2, 64); oi = __shfl_xor(idx, 2, 64); os = __shfl_xor(ws, 2, 64);
            if (ov > v || (ov == v && oi < idx)) { v = ov; idx = oi; ws = os; }
            if (lane == 0) idxOut[bh*NS + r] = idx;
            if (s == ws) {
                ++h;
                if (h < NS) { hv = segVal[s][h]; hi_ = segIdx[s][h]; }
                else        { hv = -FLT_MAX;     hi_ = 0x7fffffff;  }
            }
        }
    }
}

// ---------------------------------------------------------------------------
// K3: cumsum(v) along L.  Fused single kernel, 256 blocks = bh x 4
// column-groups (4 f4 cols each), XCD-swizzled.
// ---------------------------------------------------------------------------
__global__ __launch_bounds__(256) void cumsum_fused(
    const float* __restrict__ v, float* __restrict__ out)
{
    __shared__ float4 part[64][5];        // [sub][col], pad 4->5 (bank spread)
    int b = blockIdx.x;
    int xcd = b & 7, s = b >> 3;          // s in 0..31
    int bh  = xcd + ((s >> 2) << 3);      // 8 bh per XCD
    int cg  = s & 3;                      // column group: f4 cols 4cg..4cg+3
    int col = threadIdx.x & 3, sub = threadIdx.x >> 2;   // sub 0..63
    int c0 = cg*4 + col;                  // f4 column 0..15
    int r0 = sub * 32;                    // stripe start row
    const float4* vb = (const float4*)(v + (size_t)bh * L_ * D_);
    float4*       ob = (float4*)(out + (size_t)bh * L_ * D_);

    float4 acc = make_float4(0,0,0,0);
    #pragma unroll
    for (int r = 0; r < 32; ++r) {
        float4 x = vb[(size_t)(r0 + r)*16 + c0];
        acc.x += x.x; acc.y += x.y; acc.z += x.z; acc.w += x.w;
    }
    part[sub][col] = acc;
    __syncthreads();

    float4 run = make_float4(0,0,0,0);    // exclusive prefix of stripes 0..sub-1
    for (int cc = 0; cc < sub; ++cc) {
        float4 x = part[cc][col];
        run.x += x.x; run.y += x.y; run.z += x.z; run.w += x.w;
    }

    #pragma unroll
    for (int r = 0; r < 32; ++r) {
        float4 x = vb[(size_t)(r0 + r)*16 + c0];
        run.x += x.x; run.y += x.y; run.z += x.z; run.w += x.w;
        ob[(size_t)(r0 + r)*16 + c0] = run;
    }
}

// ---------------------------------------------------------------------------
// K4a: scores + softmax fused.  Block = (bh, group of 4 ranks), one wave per
// rank, XCD-swizzled (k slice L2-resident).  Writes normalized weights
// (zeros past qrow).
// ---------------------------------------------------------------------------
__global__ __launch_bounds__(256) void scores_kernel(
    const float* __restrict__ q, const float* __restrict__ k,
    const int* __restrict__ idxSel, float* __restrict__ attn)
{
    __shared__ float4 kbuf[16 * 129];   // [g][j], stride 129 f4
    int b = blockIdx.x;
    int xcd = b & 7, s = b >> 3;          // s in 0..79
    int bh  = xcd + ((s / 10) << 3);
    int grp = s % 10;
    int qi = threadIdx.x >> 6, sub = threadIdx.x & 63;
    int rank = grp*4 + qi;
    int qrow = idxSel[bh*NS + rank];

    const float4* qrp = (const float4*)(q + ((size_t)bh * L_ + qrow) * D_);
    float4 qreg[16];
    #pragma unroll
    for (int g = 0; g < 16; ++g) qreg[g] = qrp[g];    // wave-uniform

    const float4* kb = (const float4*)(k + (size_t)bh * L_ * D_);
    float sc0[16], sc1[16];

    #pragma unroll
    for (int c = 0; c < 16; ++c) {
        __syncthreads();                               // kbuf reuse guard
        int j0 = c * 128;
        #pragma unroll
        for (int it = 0; it < 8; ++it) {               // coalesced stage
            int fi = threadIdx.x + 256*it;
            int g = fi & 15, j = fi >> 4;
            kbuf[g*129 + j] = kb[(size_t)(j0 + j)*16 + g];
        }
        __syncthreads();
        float acc0 = 0.f, acc1 = 0.f;
        #pragma unroll
        for (int g = 0; g < 16; ++g) {
            float4 k0 = kbuf[g*129 + sub];             // dense b128
            float4 k1 = kbuf[g*129 + sub + 64];
            float4 qq = qreg[g];
            acc0 += qq.x*k0.x + qq.y*k0.y + qq.z*k0.z + qq.w*k0.w;
            acc1 += qq.x*k1.x + qq.y*k1.y + qq.z*k1.z + qq.w*k1.w;
        }
        sc0[c] = acc0 * SCALE;
        sc1[c] = acc1 * SCALE;
    }

    // masked softmax, wave-local (row lives in sc0/sc1)
    float mx = -FLT_MAX;
    #pragma unroll
    for (int c = 0; c < 16; ++c) {
        if (c*128 + sub      <= qrow) mx = fmaxf(mx, sc0[c]);
        if (c*128 + sub + 64 <= qrow) mx = fmaxf(mx, sc1[c]);
    }
    #pragma unroll
    for (int off = 32; off; off >>= 1) mx = fmaxf(mx, __shfl_xor(mx, off, 64));

    float sum = 0.f;
    #pragma unroll
    for (int c = 0; c < 16; ++c) {
        sc0[c] = (c*128 + sub      <= qrow) ? __expf(sc0[c] - mx) : 0.f;
        sc1[c] = (c*128 + sub + 64 <= qrow) ? __expf(sc1[c] - mx) : 0.f;
        sum += sc0[c] + sc1[c];
    }
    #pragma unroll
    for (int off = 32; off; off >>= 1) sum += __shfl_xor(sum, off, 64);
    float inv = 1.f / sum;

    float* arow = attn + (size_t)(bh*NS + rank) * L_;
    #pragma unroll
    for (int c = 0; c < 16; ++c) {
        arow[c*128 + sub]      = sc0[c] * inv;         // coalesced
        arow[c*128 + sub + 64] = sc1[c] * inv;
    }
}

// ---------------------------------------------------------------------------
// K4b: out[bh, qrow_r, :] = attn_row_r @ v for 4 ranks per block,
// XCD-swizzled (v + attn slices L2-resident).
// ---------------------------------------------------------------------------
__global__ __launch_bounds__(256) void pv_kernel(
    const float* __restrict__ v, const int* __restrict__ idxSel,
    const float* __restrict__ attn, float* __restrict__ out)
{
    __shared__ float wl[4][L_ + 64];    // per-rank weights, j + 4*(j>>7) pad
    __shared__ float4 part[16][16];
    __shared__ int qr4[4];
    int b = blockIdx.x;
    int xcd = b & 7, s = b >> 3;          // s in 0..79
    int bh  = xcd + ((s / 10) << 3);
    int grp = s % 10;
    int t = threadIdx.x;
    if (t < 4) qr4[t] = idxSel[bh*NS + grp*4 + t];

    // stage 4 weight rows (coalesced f4 loads)
    #pragma unroll
    for (int it = 0; it < 8; ++it) {
        int f = t + 256*it;             // 0..2047 f4 across 4 rows
        int rr = f >> 9, fi = f & 511;
        const float4* ar = (const float4*)(attn + (size_t)(bh*NS + grp*4 + rr) * L_);
        float4 x = ar[fi];
        int j = 4*fi;
        *((float4*)&wl[rr][j + 4*(j >> 7)]) = x;
    }
    __syncthreads();

    int maxq = max(max(qr4[0], qr4[1]), max(qr4[2], qr4[3]));
    int d4 = t & 15, seg = t >> 4;
    const float4* vb = (const float4*)(v + (size_t)bh * L_ * D_);
    float4 acc[4];
    #pragma unroll
    for (int rr = 0; rr < 4; ++rr) acc[rr] = make_float4(0,0,0,0);

    int jlo = seg*128, jhi = min(jlo + 127, maxq);
    for (int j = jlo; j <= jhi; ++j) {
        float4 x = vb[(size_t)j*16 + d4];          // read once
        int jp = j + 4*(j >> 7);
        #pragma unroll
        for (int rr = 0; rr < 4; ++rr) {
            float wgt = wl[rr][jp];                // 2-way conflict (free)
            acc[rr].x += wgt*x.x; acc[rr].y += wgt*x.y;
            acc[rr].z += wgt*x.z; acc[rr].w += wgt*x.w;
        }
    }

    #pragma unroll
    for (int rr = 0; rr < 4; ++rr) {
        part[seg][d4] = acc[rr];
        __syncthreads();
        float4 a = acc[rr];
        for (int s2 = 8; s2; s2 >>= 1) {
            if (seg < s2) {
                float4 o = part[seg + s2][d4];
                a.x += o.x; a.y += o.y; a.z += o.z; a.w += o.w;
                part[seg][d4] = a;
            }
            __syncthreads();
        }
        if (seg == 0) {
            float4* orow = (float4*)(out + ((size_t)bh * L_ + qr4[rr]) * D_);
            orow[d4] = a;
        }
        __syncthreads();                // before part reuse
    }
}

// ---------------------------------------------------------------------------
extern "C" void kernel_launch(void* const* d_in, const int* in_sizes, int n_in,
                              void* d_out, int out_size, void* d_ws, size_t ws_size,
                              hipStream_t stream) {
    const float* q    = (const float*)d_in[0];
    const float* k    = (const float*)d_in[1];
    const float* v    = (const float*)d_in[2];
    const int*   ridx = (const int*)d_in[3];

    float* out     = (float*)d_out;                    // (B,H,L,D)
    float* attnOut = out + (size_t)BH * L_ * D_;       // (B,H,NS,L)

    float*  measure = (float*)d_ws;                                          // BH*L floats
    int*    idxSel  = (int*)((char*)d_ws + (size_t)BH * L_ * sizeof(float)); // BH*NS ints

    measure_kernel<<<256,        512, 0, stream>>>(q, k, ridx, measure);
    topk_kernel   <<<BH,         256, 0, stream>>>(measure, idxSel);
    cumsum_fused  <<<BH * 4,     256, 0, stream>>>(v, out);
    scores_kernel <<<BH * 10,    256, 0, stream>>>(q, k, idxSel, attnOut);
    pv_kernel     <<<BH * 10,    256, 0, stream>>>(v, idxSel, attnOut, out);
}

// Round 8
// 352.601 us; speedup vs baseline: 1.4341x; 1.4341x over previous
//
#include <hip/hip_runtime.h>
#include <float.h>
#include <math.h>

#define B_  8
#define H_  8
#define L_  2048
#define D_  64
#define NS  40          // num selected = min(5*ceil(ln(2048)), 2048) = 40
#define BH  (B_*H_)
#define SCALE 0.125f    // d^-0.5

// XCD swizzle: MI355X dispatches block b to XCD (b % 8).  We remap so that
// bh % 8 == b % 8 for every kernel -> all blocks of one bh run on one XCD,
// keeping that bh's k/v/measure/attn slices resident in its 4MB L2.

// DPP helper: x += lane_shifted_down_by<SHR>(x), within rows of 16 lanes,
// out-of-row reads return 0 (bound_ctrl).  Pure VALU - no LDS pipe.
template<int CTRL>
__device__ __forceinline__ float dpp_add(float x) {
    int s = __builtin_amdgcn_update_dpp(0, __float_as_int(x), CTRL, 0xF, 0xF, true);
    return x + __int_as_float(s);
}

// ---------------------------------------------------------------------------
// K1: sparsity measure.  REVERTED to the R6 form (78.9us measured).  R7's
// LDS-tiled rewrite regressed to 273us: 128KB LDS -> 1 block/CU (23% occ),
// 8.3M bank conflicts, q re-read per tile (FETCH 34->86MB), and ~50 serial
// cross-lane ops per query-tile.  The direct L2 gather at ~79us (L2
// scattered-line throughput, ~160 64B lines/wave) is measure's floor here.
// ---------------------------------------------------------------------------
__global__ __launch_bounds__(256) void measure_kernel(
    const float* __restrict__ q, const float* __restrict__ k,
    const int* __restrict__ ridx, float* __restrict__ measure)
{
    int wave = threadIdx.x >> 6, lane = threadIdx.x & 63;
    int b = blockIdx.x;
    int xcd = b & 7, s = b >> 3;          // s in 0..4095
    int bh  = xcd + ((s >> 9) << 3);      // 8 bh per XCD, sequential
    int i   = (s & 511) * 4 + wave;       // query row within bh
    int oct = lane >> 3;                  // octet id 0..7 (row owner)
    int e   = lane & 7;                   // f4 slot within half-row

    // octet o handles samples 4o..4o+3 (one aligned int4) and 32+o (int).
    int4 r4 = *(const int4*)(ridx + i * NS + oct * 4);
    int  r5 = ridx[i * NS + 32 + oct];
    int rr[5] = { r4.x, r4.y, r4.z, r4.w, r5 };

    const float4* kb = (const float4*)(k + (size_t)bh * L_ * D_);
    const float4* qp = (const float4*)(q + ((size_t)bh * L_ + i) * D_);
    float4 qa = qp[e];          // dims 4e .. 4e+3
    float4 qb = qp[e + 8];      // dims 32+4e .. 32+4e+3

    float mx = -FLT_MAX, sm = 0.f;
    #pragma unroll
    for (int p = 0; p < 5; ++p) {
        int base = rr[p] << 4;                   // f4 index of row start
        float4 ka = kb[base + e];                // 8 lanes cover half the row
        float4 kc = kb[base + 8 + e];            // ... and the other half
        float pa = qa.x*ka.x + qa.y*ka.y + qa.z*ka.z + qa.w*ka.w;
        float pb = qb.x*kc.x + qb.y*kc.y + qb.z*kc.z + qb.w*kc.w;
        float pp = pa + pb;                      // 8-dim partial per lane
        // octet tree-sum: after shr1/2/4, lane 8o+7 = full dot(q, k[r])
        pp = dpp_add<0x111>(pp);                 // row_shr:1
        pp = dpp_add<0x112>(pp);                 // row_shr:2
        pp = dpp_add<0x114>(pp);                 // row_shr:4
        mx = fmaxf(mx, pp);                      // valid only in holder lanes
        sm += pp;
    }
    // holder lanes {7,15,...,63} each carry stats over their 5 samples;
    // xor partners of holders are holders, so 3 xor steps combine all 8.
    mx = fmaxf(mx, __shfl_xor(mx,  8, 64));  sm += __shfl_xor(sm,  8, 64);
    mx = fmaxf(mx, __shfl_xor(mx, 16, 64));  sm += __shfl_xor(sm, 16, 64);
    mx = fmaxf(mx, __shfl_xor(mx, 32, 64));  sm += __shfl_xor(sm, 32, 64);
    if (lane == 7)
        measure[(size_t)bh * L_ + i] = mx - sm * (1.0f / (float)L_);
}

// ---------------------------------------------------------------------------
// K2: top-NS per (b,h).  Barrier-free segmented tournament: each wave
// extracts its 512-row segment's sorted top-40 in-wave, one barrier, wave 0
// merges the 4 sorted lists.  Comparator: (value desc, index asc).
// ---------------------------------------------------------------------------
__global__ __launch_bounds__(256) void topk_kernel(
    const float* __restrict__ measure, int* __restrict__ idxOut)
{
    __shared__ float segVal[4][NS];
    __shared__ int   segIdx[4][NS];
    int bh = blockIdx.x;
    int t = threadIdx.x, w = t >> 6, lane = t & 63;
    const float4* m4 = (const float4*)(measure + (size_t)bh * L_);

    float vals[8];
    float4 a  = m4[128*w + 2*lane];
    float4 bb = m4[128*w + 2*lane + 1];
    vals[0]=a.x;  vals[1]=a.y;  vals[2]=a.z;  vals[3]=a.w;
    vals[4]=bb.x; vals[5]=bb.y; vals[6]=bb.z; vals[7]=bb.w;
    int gbase = 512*w + 8*lane;

    float lv = -FLT_MAX; int li = 0x7fffffff;
    #pragma unroll
    for (int e = 0; e < 8; ++e)
        if (vals[e] > lv) { lv = vals[e]; li = gbase + e; }

    for (int r = 0; r < NS; ++r) {
        float v = lv; int idx = li;
        #pragma unroll
        for (int off = 32; off; off >>= 1) {
            float ov = __shfl_xor(v, off, 64);
            int   oi = __shfl_xor(idx, off, 64);
            if (ov > v || (ov == v && oi < idx)) { v = ov; idx = oi; }
        }
        if (lane == 0) { segVal[w][r] = v; segIdx[w][r] = idx; }
        if (((idx >> 3) & 63) == lane) {
            int slot = idx & 7;
            #pragma unroll
            for (int e = 0; e < 8; ++e) if (e == slot) vals[e] = -FLT_MAX;
            lv = -FLT_MAX; li = 0x7fffffff;
            #pragma unroll
            for (int e = 0; e < 8; ++e)
                if (vals[e] > lv) { lv = vals[e]; li = gbase + e; }
        }
    }
    __syncthreads();

    if (w == 0) {
        int s = lane & 3;
        int h = 0;
        float hv = segVal[s][0]; int hi_ = segIdx[s][0];
        for (int r = 0; r < NS; ++r) {
            float v = hv; int idx = hi_; int ws = s;
            float ov = __shfl_xor(v, 1, 64); int oi = __shfl_xor(idx, 1, 64); int os = __shfl_xor(ws, 1, 64);
            if (ov > v || (ov == v && oi < idx)) { v = ov; idx = oi; ws = os; }
            ov = __shfl_xor(v, 2, 64); oi = __shfl_xor(idx, 2, 64); os = __shfl_xor(ws, 2, 64);
            if (ov > v || (ov == v && oi < idx)) { v = ov; idx = oi; ws = os; }
            if (lane == 0) idxOut[bh*NS + r] = idx;
            if (s == ws) {
                ++h;
                if (h < NS) { hv = segVal[s][h]; hi_ = segIdx[s][h]; }
                else        { hv = -FLT_MAX;     hi_ = 0x7fffffff;  }
            }
        }
    }
}

// ---------------------------------------------------------------------------
// K3: cumsum(v) along L.  Fused single kernel, 256 blocks = bh x 4
// column-groups (4 f4 cols each), XCD-swizzled.
// ---------------------------------------------------------------------------
__global__ __launch_bounds__(256) void cumsum_fused(
    const float* __restrict__ v, float* __restrict__ out)
{
    __shared__ float4 part[64][5];        // [sub][col], pad 4->5 (bank spread)
    int b = blockIdx.x;
    int xcd = b & 7, s = b >> 3;          // s in 0..31
    int bh  = xcd + ((s >> 2) << 3);      // 8 bh per XCD
    int cg  = s & 3;                      // column group: f4 cols 4cg..4cg+3
    int col = threadIdx.x & 3, sub = threadIdx.x >> 2;   // sub 0..63
    int c0 = cg*4 + col;                  // f4 column 0..15
    int r0 = sub * 32;                    // stripe start row
    const float4* vb = (const float4*)(v + (size_t)bh * L_ * D_);
    float4*       ob = (float4*)(out + (size_t)bh * L_ * D_);

    float4 acc = make_float4(0,0,0,0);
    #pragma unroll
    for (int r = 0; r < 32; ++r) {
        float4 x = vb[(size_t)(r0 + r)*16 + c0];
        acc.x += x.x; acc.y += x.y; acc.z += x.z; acc.w += x.w;
    }
    part[sub][col] = acc;
    __syncthreads();

    float4 run = make_float4(0,0,0,0);    // exclusive prefix of stripes 0..sub-1
    for (int cc = 0; cc < sub; ++cc) {
        float4 x = part[cc][col];
        run.x += x.x; run.y += x.y; run.z += x.z; run.w += x.w;
    }

    #pragma unroll
    for (int r = 0; r < 32; ++r) {
        float4 x = vb[(size_t)(r0 + r)*16 + c0];
        run.x += x.x; run.y += x.y; run.z += x.z; run.w += x.w;
        ob[(size_t)(r0 + r)*16 + c0] = run;
    }
}

// ---------------------------------------------------------------------------
// K4: scores + softmax + PV, FUSED.  Block = (bh, group of 4 ranks), one
// wave per rank for the scores phase, then whole block cooperates on PV.
// Weights pass through LDS (union with kbuf - temporally disjoint, barrier
// guarded); attn is still written to global (it's an output).  Removes the
// old pv_kernel launch + its 21MB attn re-read + its staging phase.
// ---------------------------------------------------------------------------
__global__ __launch_bounds__(256) void scores_pv_kernel(
    const float* __restrict__ q, const float* __restrict__ k,
    const int* __restrict__ idxSel, float* __restrict__ attn,
    const float* __restrict__ v, float* __restrict__ out)
{
    // union: kbuf (scores phase, 16*129 f4 = 33024B) / wl (pv phase,
    // 4*(L_+64) floats = 33792B).  Barrier separates the two uses.
    __shared__ __align__(16) float4 smraw[2112];       // 33792 B
    float4* kbuf = smraw;                              // [g][j], stride 129
    float*  wl   = (float*)smraw;                      // [4][L_+64], j+4*(j>>7) pad
    __shared__ float4 part[16][16];
    __shared__ int qr4[4];

    int b = blockIdx.x;
    int xcd = b & 7, s = b >> 3;          // s in 0..79
    int bh  = xcd + ((s / 10) << 3);
    int grp = s % 10;
    int t = threadIdx.x;
    int qi = t >> 6, sub = t & 63;
    int rank = grp*4 + qi;
    int qrow = idxSel[bh*NS + rank];

    const float4* qrp = (const float4*)(q + ((size_t)bh * L_ + qrow) * D_);
    float4 qreg[16];
    #pragma unroll
    for (int g = 0; g < 16; ++g) qreg[g] = qrp[g];    // wave-uniform

    const float4* kb = (const float4*)(k + (size_t)bh * L_ * D_);
    float sc0[16], sc1[16];

    #pragma unroll
    for (int c = 0; c < 16; ++c) {
        __syncthreads();                               // kbuf reuse guard
        int j0 = c * 128;
        #pragma unroll
        for (int it = 0; it < 8; ++it) {               // coalesced stage
            int fi = t + 256*it;
            int g = fi & 15, j = fi >> 4;
            kbuf[g*129 + j] = kb[(size_t)(j0 + j)*16 + g];
        }
        __syncthreads();
        float acc0 = 0.f, acc1 = 0.f;
        #pragma unroll
        for (int g = 0; g < 16; ++g) {
            float4 k0 = kbuf[g*129 + sub];             // dense b128
            float4 k1 = kbuf[g*129 + sub + 64];
            float4 qq = qreg[g];
            acc0 += qq.x*k0.x + qq.y*k0.y + qq.z*k0.z + qq.w*k0.w;
            acc1 += qq.x*k1.x + qq.y*k1.y + qq.z*k1.z + qq.w*k1.w;
        }
        sc0[c] = acc0 * SCALE;
        sc1[c] = acc1 * SCALE;
    }

    // masked softmax, wave-local (row lives in sc0/sc1)
    float mx = -FLT_MAX;
    #pragma unroll
    for (int c = 0; c < 16; ++c) {
        if (c*128 + sub      <= qrow) mx = fmaxf(mx, sc0[c]);
        if (c*128 + sub + 64 <= qrow) mx = fmaxf(mx, sc1[c]);
    }
    #pragma unroll
    for (int off = 32; off; off >>= 1) mx = fmaxf(mx, __shfl_xor(mx, off, 64));

    float sum = 0.f;
    #pragma unroll
    for (int c = 0; c < 16; ++c) {
        sc0[c] = (c*128 + sub      <= qrow) ? __expf(sc0[c] - mx) : 0.f;
        sc1[c] = (c*128 + sub + 64 <= qrow) ? __expf(sc1[c] - mx) : 0.f;
        sum += sc0[c] + sc1[c];
    }
    #pragma unroll
    for (int off = 32; off; off >>= 1) sum += __shfl_xor(sum, off, 64);
    float inv = 1.f / sum;

    __syncthreads();        // ALL waves done reading kbuf before wl overwrite

    // weights -> LDS (for PV) and -> global attn (output), coalesced
    float* wlr = wl + qi * (L_ + 64);
    float* arow = attn + (size_t)(bh*NS + rank) * L_;
    #pragma unroll
    for (int c = 0; c < 16; ++c) {
        float w0 = sc0[c] * inv, w1 = sc1[c] * inv;
        int j0 = c*128 + sub, j1 = j0 + 64;
        wlr[j0 + 4*(j0 >> 7)] = w0;
        wlr[j1 + 4*(j1 >> 7)] = w1;
        arow[j0] = w0;
        arow[j1] = w1;
    }
    if (sub == 0) qr4[qi] = qrow;
    __syncthreads();

    // ---- PV phase: out[bh, qrow_r, :] = w_r . v ----
    int maxq = max(max(qr4[0], qr4[1]), max(qr4[2], qr4[3]));
    int d4 = t & 15, seg = t >> 4;
    const float4* vb = (const float4*)(v + (size_t)bh * L_ * D_);
    float4 acc[4];
    #pragma unroll
    for (int rr = 0; rr < 4; ++rr) acc[rr] = make_float4(0,0,0,0);

    int jlo = seg*128, jhi = min(jlo + 127, maxq);
    for (int j = jlo; j <= jhi; ++j) {
        float4 x = vb[(size_t)j*16 + d4];          // read once
        int jp = j + 4*(j >> 7);
        #pragma unroll
        for (int rr = 0; rr < 4; ++rr) {
            float wgt = wl[rr*(L_ + 64) + jp];     // 2-way conflict (free)
            acc[rr].x += wgt*x.x; acc[rr].y += wgt*x.y;
            acc[rr].z += wgt*x.z; acc[rr].w += wgt*x.w;
        }
    }

    #pragma unroll
    for (int rr = 0; rr < 4; ++rr) {
        part[seg][d4] = acc[rr];
        __syncthreads();
        float4 a = acc[rr];
        for (int s2 = 8; s2; s2 >>= 1) {
            if (seg < s2) {
                float4 o = part[seg + s2][d4];
                a.x += o.x; a.y += o.y; a.z += o.z; a.w += o.w;
                part[seg][d4] = a;
            }
            __syncthreads();
        }
        if (seg == 0) {
            float4* orow = (float4*)(out + ((size_t)bh * L_ + qr4[rr]) * D_);
            orow[d4] = a;
        }
        __syncthreads();                // before part reuse
    }
}

// ---------------------------------------------------------------------------
extern "C" void kernel_launch(void* const* d_in, const int* in_sizes, int n_in,
                              void* d_out, int out_size, void* d_ws, size_t ws_size,
                              hipStream_t stream) {
    const float* q    = (const float*)d_in[0];
    const float* k    = (const float*)d_in[1];
    const float* v    = (const float*)d_in[2];
    const int*   ridx = (const int*)d_in[3];

    float* out     = (float*)d_out;                    // (B,H,L,D)
    float* attnOut = out + (size_t)BH * L_ * D_;       // (B,H,NS,L)

    float*  measure = (float*)d_ws;                                          // BH*L floats
    int*    idxSel  = (int*)((char*)d_ws + (size_t)BH * L_ * sizeof(float)); // BH*NS ints

    measure_kernel  <<<BH * L_ / 4, 256, 0, stream>>>(q, k, ridx, measure);
    topk_kernel     <<<BH,          256, 0, stream>>>(measure, idxSel);
    cumsum_fused    <<<BH * 4,      256, 0, stream>>>(v, out);
    scores_pv_kernel<<<BH * 10,     256, 0, stream>>>(q, k, idxSel, attnOut, v, out);
}

// Round 9
// 322.397 us; speedup vs baseline: 1.5684x; 1.0937x over previous
//
#include <hip/hip_runtime.h>
#include <float.h>
#include <math.h>

#define B_  8
#define H_  8
#define L_  2048
#define D_  64
#define NS  40          // num selected = min(5*ceil(ln(2048)), 2048) = 40
#define BH  (B_*H_)
#define SCALE 0.125f    // d^-0.5

// XCD swizzle: MI355X dispatches block b to XCD (b % 8).  We remap so that
// bh % 8 == b % 8 for every kernel -> all blocks of one bh run on one XCD,
// keeping that bh's k/v/measure/attn slices resident in its 4MB L2.

// DPP helper: x += lane_shifted_down_by<SHR>(x), within rows of 16 lanes,
// out-of-row reads return 0 (bound_ctrl).  Pure VALU - no LDS pipe.
template<int CTRL>
__device__ __forceinline__ float dpp_add(float x) {
    int s = __builtin_amdgcn_update_dpp(0, __float_as_int(x), CTRL, 0xF, 0xF, true);
    return x + __int_as_float(s);
}

// ---------------------------------------------------------------------------
// K1: measure + cumsum, GRID-FUSED into one launch.  The two are fully
// independent (measure: q,k,ridx -> ws; cumsum: v -> out).  measure is
// latency-bound (HBM 5.5%, VALU 34%) so the 256 cumsum blocks stream v
// through the idle memory slack - hides cumsum's ~30us under measure's 79.
// cumsum blocks come FIRST (dispatch order) so they overlap the full launch.
//
// measure (blocks 256..4351): one wave per query, octet gather+DPP dot.
// Bound by L2 scattered-line throughput (~79us floor; see R7 post-mortem -
// LDS tiling made it 3.4x worse).
// cumsum (blocks 0..255): bh x 4 column-groups; stripe totals -> LDS ->
// exclusive prefix -> second pass with running sum.
// ---------------------------------------------------------------------------
__global__ __launch_bounds__(256) void measure_cumsum_kernel(
    const float* __restrict__ q, const float* __restrict__ k,
    const int* __restrict__ ridx, float* __restrict__ measure,
    const float* __restrict__ v, float* __restrict__ out)
{
    __shared__ float4 part[64][5];        // cumsum only; 5.1KB, no occ impact
    if (blockIdx.x < 256) {
        // ---------------- cumsum ----------------
        int b = blockIdx.x;
        int xcd = b & 7, s = b >> 3;          // s in 0..31
        int bh  = xcd + ((s >> 2) << 3);      // 8 bh per XCD
        int cg  = s & 3;                      // column group: f4 cols 4cg..4cg+3
        int col = threadIdx.x & 3, sub = threadIdx.x >> 2;   // sub 0..63
        int c0 = cg*4 + col;
        int r0 = sub * 32;
        const float4* vb = (const float4*)(v + (size_t)bh * L_ * D_);
        float4*       ob = (float4*)(out + (size_t)bh * L_ * D_);

        float4 acc = make_float4(0,0,0,0);
        #pragma unroll
        for (int r = 0; r < 32; ++r) {
            float4 x = vb[(size_t)(r0 + r)*16 + c0];
            acc.x += x.x; acc.y += x.y; acc.z += x.z; acc.w += x.w;
        }
        part[sub][col] = acc;
        __syncthreads();

        float4 run = make_float4(0,0,0,0);    // exclusive prefix of stripes
        for (int cc = 0; cc < sub; ++cc) {
            float4 x = part[cc][col];
            run.x += x.x; run.y += x.y; run.z += x.z; run.w += x.w;
        }

        #pragma unroll
        for (int r = 0; r < 32; ++r) {
            float4 x = vb[(size_t)(r0 + r)*16 + c0];
            run.x += x.x; run.y += x.y; run.z += x.z; run.w += x.w;
            ob[(size_t)(r0 + r)*16 + c0] = run;
        }
        return;
    }
    // ---------------- measure ----------------
    int wave = threadIdx.x >> 6, lane = threadIdx.x & 63;
    int b = blockIdx.x - 256;                 // 256 = 0 mod 8: b&7 swizzle kept
    int xcd = b & 7, s = b >> 3;              // s in 0..4095
    int bh  = xcd + ((s >> 9) << 3);          // 8 bh per XCD, sequential
    int i   = (s & 511) * 4 + wave;           // query row within bh
    int oct = lane >> 3;                      // octet id 0..7 (row owner)
    int e   = lane & 7;                       // f4 slot within half-row

    // octet o handles samples 4o..4o+3 (one aligned int4) and 32+o (int).
    int4 r4 = *(const int4*)(ridx + i * NS + oct * 4);
    int  r5 = ridx[i * NS + 32 + oct];
    int rr[5] = { r4.x, r4.y, r4.z, r4.w, r5 };

    const float4* kb = (const float4*)(k + (size_t)bh * L_ * D_);
    const float4* qp = (const float4*)(q + ((size_t)bh * L_ + i) * D_);
    float4 qa = qp[e];          // dims 4e .. 4e+3
    float4 qb = qp[e + 8];      // dims 32+4e .. 32+4e+3

    float mx = -FLT_MAX, sm = 0.f;
    #pragma unroll
    for (int p = 0; p < 5; ++p) {
        int base = rr[p] << 4;                   // f4 index of row start
        float4 ka = kb[base + e];                // 8 lanes cover half the row
        float4 kc = kb[base + 8 + e];            // ... and the other half
        float pa = qa.x*ka.x + qa.y*ka.y + qa.z*ka.z + qa.w*ka.w;
        float pb = qb.x*kc.x + qb.y*kc.y + qb.z*kc.z + qb.w*kc.w;
        float pp = pa + pb;                      // 8-dim partial per lane
        // octet tree-sum: after shr1/2/4, lane 8o+7 = full dot(q, k[r])
        pp = dpp_add<0x111>(pp);                 // row_shr:1
        pp = dpp_add<0x112>(pp);                 // row_shr:2
        pp = dpp_add<0x114>(pp);                 // row_shr:4
        mx = fmaxf(mx, pp);                      // valid only in holder lanes
        sm += pp;
    }
    // holder lanes {7,15,...,63}; xor partners of holders are holders.
    mx = fmaxf(mx, __shfl_xor(mx,  8, 64));  sm += __shfl_xor(sm,  8, 64);
    mx = fmaxf(mx, __shfl_xor(mx, 16, 64));  sm += __shfl_xor(sm, 16, 64);
    mx = fmaxf(mx, __shfl_xor(mx, 32, 64));  sm += __shfl_xor(sm, 32, 64);
    if (lane == 7)
        measure[(size_t)bh * L_ + i] = mx - sm * (1.0f / (float)L_);
}

// ---------------------------------------------------------------------------
// K2: top-NS per (b,h).  Barrier-free segmented tournament: each wave
// extracts its 512-row segment's sorted top-40 in-wave, one barrier, wave 0
// merges the 4 sorted lists.  Comparator: (value desc, index asc).
// ---------------------------------------------------------------------------
__global__ __launch_bounds__(256) void topk_kernel(
    const float* __restrict__ measure, int* __restrict__ idxOut)
{
    __shared__ float segVal[4][NS];
    __shared__ int   segIdx[4][NS];
    int bh = blockIdx.x;
    int t = threadIdx.x, w = t >> 6, lane = t & 63;
    const float4* m4 = (const float4*)(measure + (size_t)bh * L_);

    float vals[8];
    float4 a  = m4[128*w + 2*lane];
    float4 bb = m4[128*w + 2*lane + 1];
    vals[0]=a.x;  vals[1]=a.y;  vals[2]=a.z;  vals[3]=a.w;
    vals[4]=bb.x; vals[5]=bb.y; vals[6]=bb.z; vals[7]=bb.w;
    int gbase = 512*w + 8*lane;

    float lv = -FLT_MAX; int li = 0x7fffffff;
    #pragma unroll
    for (int e = 0; e < 8; ++e)
        if (vals[e] > lv) { lv = vals[e]; li = gbase + e; }

    for (int r = 0; r < NS; ++r) {
        float v = lv; int idx = li;
        #pragma unroll
        for (int off = 32; off; off >>= 1) {
            float ov = __shfl_xor(v, off, 64);
            int   oi = __shfl_xor(idx, off, 64);
            if (ov > v || (ov == v && oi < idx)) { v = ov; idx = oi; }
        }
        if (lane == 0) { segVal[w][r] = v; segIdx[w][r] = idx; }
        if (((idx >> 3) & 63) == lane) {
            int slot = idx & 7;
            #pragma unroll
            for (int e = 0; e < 8; ++e) if (e == slot) vals[e] = -FLT_MAX;
            lv = -FLT_MAX; li = 0x7fffffff;
            #pragma unroll
            for (int e = 0; e < 8; ++e)
                if (vals[e] > lv) { lv = vals[e]; li = gbase + e; }
        }
    }
    __syncthreads();

    if (w == 0) {
        int s = lane & 3;
        int h = 0;
        float hv = segVal[s][0]; int hi_ = segIdx[s][0];
        for (int r = 0; r < NS; ++r) {
            float v = hv; int idx = hi_; int ws = s;
            float ov = __shfl_xor(v, 1, 64); int oi = __shfl_xor(idx, 1, 64); int os = __shfl_xor(ws, 1, 64);
            if (ov > v || (ov == v && oi < idx)) { v = ov; idx = oi; ws = os; }
            ov = __shfl_xor(v, 2, 64); oi = __shfl_xor(idx, 2, 64); os = __shfl_xor(ws, 2, 64);
            if (ov > v || (ov == v && oi < idx)) { v = ov; idx = oi; ws = os; }
            if (lane == 0) idxOut[bh*NS + r] = idx;
            if (s == ws) {
                ++h;
                if (h < NS) { hv = segVal[s][h]; hi_ = segIdx[s][h]; }
                else        { hv = -FLT_MAX;     hi_ = 0x7fffffff;  }
            }
        }
    }
}

// ---------------------------------------------------------------------------
// K4a: scores + softmax fused (R6 version, un-fused from PV: the R8 fusion
// serialized the phases in-block and cost 13.9% occupancy -> +27us total).
// Block = (bh, group of 4 ranks), one wave per rank, XCD-swizzled.
// ---------------------------------------------------------------------------
__global__ __launch_bounds__(256) void scores_kernel(
    const float* __restrict__ q, const float* __restrict__ k,
    const int* __restrict__ idxSel, float* __restrict__ attn)
{
    __shared__ float4 kbuf[16 * 129];   // [g][j], stride 129 f4
    int b = blockIdx.x;
    int xcd = b & 7, s = b >> 3;          // s in 0..79
    int bh  = xcd + ((s / 10) << 3);
    int grp = s % 10;
    int qi = threadIdx.x >> 6, sub = threadIdx.x & 63;
    int rank = grp*4 + qi;
    int qrow = idxSel[bh*NS + rank];

    const float4* qrp = (const float4*)(q + ((size_t)bh * L_ + qrow) * D_);
    float4 qreg[16];
    #pragma unroll
    for (int g = 0; g < 16; ++g) qreg[g] = qrp[g];    // wave-uniform

    const float4* kb = (const float4*)(k + (size_t)bh * L_ * D_);
    float sc0[16], sc1[16];

    #pragma unroll
    for (int c = 0; c < 16; ++c) {
        __syncthreads();                               // kbuf reuse guard
        int j0 = c * 128;
        #pragma unroll
        for (int it = 0; it < 8; ++it) {               // coalesced stage
            int fi = threadIdx.x + 256*it;
            int g = fi & 15, j = fi >> 4;
            kbuf[g*129 + j] = kb[(size_t)(j0 + j)*16 + g];
        }
        __syncthreads();
        float acc0 = 0.f, acc1 = 0.f;
        #pragma unroll
        for (int g = 0; g < 16; ++g) {
            float4 k0 = kbuf[g*129 + sub];             // dense b128
            float4 k1 = kbuf[g*129 + sub + 64];
            float4 qq = qreg[g];
            acc0 += qq.x*k0.x + qq.y*k0.y + qq.z*k0.z + qq.w*k0.w;
            acc1 += qq.x*k1.x + qq.y*k1.y + qq.z*k1.z + qq.w*k1.w;
        }
        sc0[c] = acc0 * SCALE;
        sc1[c] = acc1 * SCALE;
    }

    // masked softmax, wave-local (row lives in sc0/sc1)
    float mx = -FLT_MAX;
    #pragma unroll
    for (int c = 0; c < 16; ++c) {
        if (c*128 + sub      <= qrow) mx = fmaxf(mx, sc0[c]);
        if (c*128 + sub + 64 <= qrow) mx = fmaxf(mx, sc1[c]);
    }
    #pragma unroll
    for (int off = 32; off; off >>= 1) mx = fmaxf(mx, __shfl_xor(mx, off, 64));

    float sum = 0.f;
    #pragma unroll
    for (int c = 0; c < 16; ++c) {
        sc0[c] = (c*128 + sub      <= qrow) ? __expf(sc0[c] - mx) : 0.f;
        sc1[c] = (c*128 + sub + 64 <= qrow) ? __expf(sc1[c] - mx) : 0.f;
        sum += sc0[c] + sc1[c];
    }
    #pragma unroll
    for (int off = 32; off; off >>= 1) sum += __shfl_xor(sum, off, 64);
    float inv = 1.f / sum;

    float* arow = attn + (size_t)(bh*NS + rank) * L_;
    #pragma unroll
    for (int c = 0; c < 16; ++c) {
        arow[c*128 + sub]      = sc0[c] * inv;         // coalesced
        arow[c*128 + sub + 64] = sc1[c] * inv;
    }
}

// ---------------------------------------------------------------------------
// K4b: out[bh, qrow_r, :] = attn_row_r @ v for 4 ranks per block,
// XCD-swizzled (v + attn slices L2-resident).  (R6 version.)
// ---------------------------------------------------------------------------
__global__ __launch_bounds__(256) void pv_kernel(
    const float* __restrict__ v, const int* __restrict__ idxSel,
    const float* __restrict__ attn, float* __restrict__ out)
{
    __shared__ float wl[4][L_ + 64];    // per-rank weights, j + 4*(j>>7) pad
    __shared__ float4 part[16][16];
    __shared__ int qr4[4];
    int b = blockIdx.x;
    int xcd = b & 7, s = b >> 3;          // s in 0..79
    int bh  = xcd + ((s / 10) << 3);
    int grp = s % 10;
    int t = threadIdx.x;
    if (t < 4) qr4[t] = idxSel[bh*NS + grp*4 + t];

    // stage 4 weight rows (coalesced f4 loads)
    #pragma unroll
    for (int it = 0; it < 8; ++it) {
        int f = t + 256*it;             // 0..2047 f4 across 4 rows
        int rr = f >> 9, fi = f & 511;
        const float4* ar = (const float4*)(attn + (size_t)(bh*NS + grp*4 + rr) * L_);
        float4 x = ar[fi];
        int j = 4*fi;
        *((float4*)&wl[rr][j + 4*(j >> 7)]) = x;
    }
    __syncthreads();

    int maxq = max(max(qr4[0], qr4[1]), max(qr4[2], qr4[3]));
    int d4 = t & 15, seg = t >> 4;
    const float4* vb = (const float4*)(v + (size_t)bh * L_ * D_);
    float4 acc[4];
    #pragma unroll
    for (int rr = 0; rr < 4; ++rr) acc[rr] = make_float4(0,0,0,0);

    int jlo = seg*128, jhi = min(jlo + 127, maxq);
    for (int j = jlo; j <= jhi; ++j) {
        float4 x = vb[(size_t)j*16 + d4];          // read once
        int jp = j + 4*(j >> 7);
        #pragma unroll
        for (int rr = 0; rr < 4; ++rr) {
            float wgt = wl[rr][jp];                // 2-way conflict (free)
            acc[rr].x += wgt*x.x; acc[rr].y += wgt*x.y;
            acc[rr].z += wgt*x.z; acc[rr].w += wgt*x.w;
        }
    }

    #pragma unroll
    for (int rr = 0; rr < 4; ++rr) {
        part[seg][d4] = acc[rr];
        __syncthreads();
        float4 a = acc[rr];
        for (int s2 = 8; s2; s2 >>= 1) {
            if (seg < s2) {
                float4 o = part[seg + s2][d4];
                a.x += o.x; a.y += o.y; a.z += o.z; a.w += o.w;
                part[seg][d4] = a;
            }
            __syncthreads();
        }
        if (seg == 0) {
            float4* orow = (float4*)(out + ((size_t)bh * L_ + qr4[rr]) * D_);
            orow[d4] = a;
        }
        __syncthreads();                // before part reuse
    }
}

// ---------------------------------------------------------------------------
extern "C" void kernel_launch(void* const* d_in, const int* in_sizes, int n_in,
                              void* d_out, int out_size, void* d_ws, size_t ws_size,
                              hipStream_t stream) {
    const float* q    = (const float*)d_in[0];
    const float* k    = (const float*)d_in[1];
    const float* v    = (const float*)d_in[2];
    const int*   ridx = (const int*)d_in[3];

    float* out     = (float*)d_out;                    // (B,H,L,D)
    float* attnOut = out + (size_t)BH * L_ * D_;       // (B,H,NS,L)

    float*  measure = (float*)d_ws;                                          // BH*L floats
    int*    idxSel  = (int*)((char*)d_ws + (size_t)BH * L_ * sizeof(float)); // BH*NS ints

    measure_cumsum_kernel<<<256 + BH * L_ / 4, 256, 0, stream>>>(
        q, k, ridx, measure, v, out);
    topk_kernel   <<<BH,          256, 0, stream>>>(measure, idxSel);
    scores_kernel <<<BH * 10,     256, 0, stream>>>(q, k, idxSel, attnOut);
    pv_kernel     <<<BH * 10,     256, 0, stream>>>(v, idxSel, attnOut, out);
}